// Round 13
// baseline (42.581 us; speedup 1.0000x reference)
//
#include <hip/hip_runtime.h>

// Problem constants (match reference)
#define BB 64
#define N_WAY 5
#define N_SHOT 5
#define QUERY 15
#define NUM_SLOT 8
#define DD 640
#define IMGS (N_WAY * QUERY)      // 75
#define NS (BB * N_WAY * N_SHOT)  // 1600 support rows
#define QROWS (BB * IMGS)         // 4800 query rows
#define ROWSZ (NUM_SLOT * DD)     // 5120 floats per row
#define F4_PER_SLOT 160           // 640/4
#define NELEM (BB * IMGS)         // 4800 loss elements
#define NGROUP (BB * N_WAY)       // 320 support groups
#define PIECES 19                 // ceil(75/4) pieces per batch
#define NBLK (BB * PIECES)        // 1216 mid blocks (1 element per wave)

// ---------------- K1: single streaming pass over out_f ----------------
// Query rows -> rowmean_q[4800][8]. Support groups -> proto_all[320][8][640],
// pn2_all[320][8], supm_g[320][8] (= mean_d proto = mean over shot,d of raw).
__global__ __launch_bounds__(256) void k_pass1(const float* __restrict__ out_f,
                                               float* __restrict__ rowmean_q,
                                               float* __restrict__ proto_all,
                                               float* __restrict__ pn2_all,
                                               float* __restrict__ supm_g) {
    int b = blockIdx.x;
    int t = threadIdx.x;
    int slot = t >> 5;            // 0..7
    int l = t & 31;
    if (b < NGROUP) {
        const int g = b;          // support group j*5+c
        float4 acc[5];
        #pragma unroll
        for (int k = 0; k < 5; ++k) acc[k] = make_float4(0.f, 0.f, 0.f, 0.f);
        #pragma unroll
        for (int sh = 0; sh < N_SHOT; ++sh) {
            const float4* p = (const float4*)(out_f +
                ((size_t)((g * N_SHOT + sh) * NUM_SLOT + slot)) * DD);
            #pragma unroll
            for (int k = 0; k < 5; ++k) {
                float4 v = p[l + k * 32];
                acc[k].x += v.x; acc[k].y += v.y; acc[k].z += v.z; acc[k].w += v.w;
            }
        }
        float4* pp = (float4*)(proto_all + ((size_t)(g * NUM_SLOT + slot)) * DD);
        float ssq = 0.f, sm = 0.f;
        #pragma unroll
        for (int k = 0; k < 5; ++k) {
            acc[k].x *= 0.2f; acc[k].y *= 0.2f; acc[k].z *= 0.2f; acc[k].w *= 0.2f;
            pp[l + k * 32] = acc[k];
            ssq += acc[k].x * acc[k].x + acc[k].y * acc[k].y
                 + acc[k].z * acc[k].z + acc[k].w * acc[k].w;
            sm  += (acc[k].x + acc[k].y) + (acc[k].z + acc[k].w);
        }
        #pragma unroll
        for (int off = 16; off; off >>= 1) {
            ssq += __shfl_down(ssq, off, 32);
            sm  += __shfl_down(sm,  off, 32);
        }
        if (l == 0) {
            pn2_all[g * NUM_SLOT + slot] = ssq;
            supm_g[g * NUM_SLOT + slot]  = sm * (1.f / DD);
        }
    } else {
        int rq = b - NGROUP;         // query row index 0..4799
        const float4* p = (const float4*)(out_f + (size_t)(NS + rq) * ROWSZ)
                          + slot * F4_PER_SLOT;
        float s = 0.f;
        #pragma unroll
        for (int k = 0; k < 5; ++k) {
            float4 v = p[l + k * 32];
            s += (v.x + v.y) + (v.z + v.w);
        }
        #pragma unroll
        for (int off = 16; off; off >>= 1) s += __shfl_down(s, off, 32);
        if (l == 0) rowmean_q[rq * NUM_SLOT + slot] = s * (1.f / DD);
    }
}

// ---------------- K2: fused mid kernel, one element per wave (R10 shape) -------
// 19 blocks/batch x 4 waves. Per block: cheap redundant setup (transposed qbt
// + select) + ONE shared LDS proto stage; per wave: argmax -> q loads -> dual
// dot vs LDS protos -> reduce -> lane0 softmax.
__global__ __launch_bounds__(256) void k_mid(const float* __restrict__ out_f,
                                             const float* __restrict__ rowmean_q,
                                             const float* __restrict__ proto_all,
                                             const float* __restrict__ pn2_all,
                                             const float* __restrict__ supm_g,
                                             const int* __restrict__ labels_query,
                                             float4* __restrict__ part) {
    int b = blockIdx.x;            // j*PIECES + piece
    int j = b / PIECES, piece = b - j * PIECES;
    int t = threadIdx.x;           // 256
    int wave = t >> 6, lane = t & 63;
    int m = piece * 4 + wave;      // element this wave owns (>=75 -> idle)

    __shared__ float qbt[NUM_SLOT][80];       // transposed query rowmeans
    __shared__ float supmS[N_WAY * NUM_SLOT];
    __shared__ int   msS[N_WAY];
    __shared__ float p2S[N_WAY];
    __shared__ __align__(16) float2 protoS[N_WAY * 5][64];   // 12.8 KB shared protos
    __shared__ float4 redS[4];

    // stage query row-means transposed (conflict-free argmax reads later)
    const float* qbase = rowmean_q + (size_t)j * IMGS * NUM_SLOT;
    if (t < 150) {
        float4 v = ((const float4*)qbase)[t];
        int s = t >> 1, sl0 = (t & 1) * 4;
        qbt[sl0 + 0][s] = v.x; qbt[sl0 + 1][s] = v.y;
        qbt[sl0 + 2][s] = v.z; qbt[sl0 + 3][s] = v.w;
    }
    // support slot-means (precomputed by pass1)
    if (t >= 192 && t < 192 + N_WAY * NUM_SLOT)
        supmS[t - 192] = supm_g[j * (N_WAY * NUM_SLOT) + (t - 192)];
    __syncthreads();

    // greedy cover select (serial, tiny; first-occurrence among untaken)
    if (t == 0) {
        unsigned taken = 0u;
        #pragma unroll
        for (int c = 0; c < N_WAY; ++c) {
            float best = -3.0e38f; int bi = 0;
            #pragma unroll
            for (int s = 0; s < NUM_SLOT; ++s) {
                float v = supmS[c * NUM_SLOT + s];
                if (!((taken >> s) & 1u) && v > best) { best = v; bi = s; }
            }
            taken |= (1u << bi);
            msS[c] = bi;
        }
    }
    __syncthreads();

    int ms[N_WAY];
    #pragma unroll
    for (int n = 0; n < N_WAY; ++n) ms[n] = msS[n];
    if (t < N_WAY) p2S[t] = pn2_all[(j * N_WAY + t) * NUM_SLOT + ms[t]];

    // issue q1 load early (row m, its class's selected slot)
    float2 q1v[5];
    if (m < IMGS) {
        const float2* q1p = (const float2*)(out_f +
            (size_t)(NS + j * IMGS + m) * ROWSZ + ms[m / QUERY] * DD) + lane * 5;
        #pragma unroll
        for (int k = 0; k < 5; ++k) q1v[k] = q1p[k];
    }

    // cooperative shared proto stage: protoS[n*5+k][lane_d] = float2 #(lane_d*5+k)
    // of selected proto n (global reads coalesced within each proto row)
    for (int idx = t; idx < N_WAY * 320; idx += 256) {
        int n = idx / 320, r = idx - n * 320;
        const float2* gp = (const float2*)(proto_all +
            ((size_t)((j * N_WAY + n) * NUM_SLOT + msS[n])) * DD);
        int lane_d = r / 5, k = r - lane_d * 5;
        protoS[n * 5 + k][lane_d] = gp[r];
    }

    // per-wave argmax over flat candidates l = s*5+c, s in [0, m]
    // (first occurrence == max value, min flat index among ties)
    float2 q2v[5];
    if (m < IMGS) {
        float bv = -3.0e38f; int bi = 0x7fffffff;
        #pragma unroll
        for (int rep = 0; rep < 2; ++rep) {
            int s = lane + rep * 64;
            if (s <= m) {
                #pragma unroll
                for (int c = 0; c < N_WAY; ++c) {
                    float x = qbt[ms[c]][s];          // consecutive -> conflict-free
                    int flat = s * N_WAY + c;
                    if (x > bv || (x == bv && flat < bi)) { bv = x; bi = flat; }
                }
            }
        }
        #pragma unroll
        for (int off = 32; off; off >>= 1) {
            float ov = __shfl_down(bv, off, 64);
            int   oi = __shfl_down(bi, off, 64);
            if (ov > bv || (ov == bv && oi < bi)) { bv = ov; bi = oi; }
        }
        bi = __shfl(bi, 0, 64);                       // broadcast winner
        int s2 = bi / N_WAY, c2 = bi - s2 * N_WAY;
        const float2* q2p = (const float2*)(out_f +
            (size_t)(NS + j * IMGS + s2) * ROWSZ + ms[c2] * DD) + lane * 5;
        #pragma unroll
        for (int k = 0; k < 5; ++k) q2v[k] = q2p[k];
    }
    __syncthreads();   // protoS ready

    float4 lv = make_float4(0.f, 0.f, 0.f, 0.f);
    if (m < IMGS) {
        float s1[N_WAY] = {0, 0, 0, 0, 0};
        float s2a[N_WAY] = {0, 0, 0, 0, 0};
        #pragma unroll
        for (int n = 0; n < N_WAY; ++n) {
            #pragma unroll
            for (int k = 0; k < 5; ++k) {
                float2 p = protoS[n * 5 + k][lane];   // lane-linear ds_read_b64
                s1[n]  += q1v[k].x * p.x + q1v[k].y * p.y;
                s2a[n] += q2v[k].x * p.x + q2v[k].y * p.y;
            }
        }
        #pragma unroll
        for (int n = 0; n < N_WAY; ++n) {
            #pragma unroll
            for (int off = 32; off; off >>= 1) {
                s1[n]  += __shfl_down(s1[n],  off, 64);
                s2a[n] += __shfl_down(s2a[n], off, 64);
            }
        }
        if (lane == 0) {
            int label = labels_query[j * IMGS + m];
            // path 1: li_n = 2 q.p_n - ||p_n||^2 (||q||^2 cancels)
            {
                float li[N_WAY]; float mx = -3.0e38f;
                #pragma unroll
                for (int n = 0; n < N_WAY; ++n) { li[n] = 2.f * s1[n] - p2S[n]; mx = fmaxf(mx, li[n]); }
                float se = 0.f;
                #pragma unroll
                for (int n = 0; n < N_WAY; ++n) se += expf(li[n] - mx);
                float lse = mx + logf(se);
                int bn = 0; float bvv = li[0];
                #pragma unroll
                for (int n = 1; n < N_WAY; ++n) if (li[n] > bvv) { bvv = li[n]; bn = n; }
                lv.x = -(li[label] - lse);
                lv.z = (bn == label) ? 1.f : 0.f;
            }
            // path 2
            {
                float li[N_WAY]; float mx = -3.0e38f;
                #pragma unroll
                for (int n = 0; n < N_WAY; ++n) { li[n] = 2.f * s2a[n] - p2S[n]; mx = fmaxf(mx, li[n]); }
                float se = 0.f;
                #pragma unroll
                for (int n = 0; n < N_WAY; ++n) se += expf(li[n] - mx);
                float lse = mx + logf(se);
                int bn = 0; float bvv = li[0];
                #pragma unroll
                for (int n = 1; n < N_WAY; ++n) if (li[n] > bvv) { bvv = li[n]; bn = n; }
                lv.y = -(li[label] - lse);
                lv.w = (bn == label) ? 1.f : 0.f;
            }
        }
    }
    if (lane == 0) redS[wave] = lv;        // idle waves write zeros
    __syncthreads();
    if (t == 0) {
        float4 s0 = redS[0], s1 = redS[1], s2 = redS[2], s3 = redS[3];
        part[b] = make_float4(s0.x + s1.x + s2.x + s3.x,
                              s0.y + s1.y + s2.y + s3.y,
                              s0.z + s1.z + s2.z + s3.z,
                              s0.w + s1.w + s2.w + s3.w);
    }
}

// ---------------- K3: final deterministic reduction (1216 float4) --------------
__global__ __launch_bounds__(256) void k_final(const float4* __restrict__ part,
                                               const float* __restrict__ att_loss,
                                               float* __restrict__ out) {
    __shared__ float4 red[256];
    int t = threadIdx.x;              // 256
    float4 s = make_float4(0.f, 0.f, 0.f, 0.f);
    for (int i = t; i < NBLK; i += 256) {
        float4 v = part[i];
        s.x += v.x; s.y += v.y; s.z += v.z; s.w += v.w;
    }
    red[t] = s;
    __syncthreads();
    for (int w = 128; w; w >>= 1) {
        if (t < w) {
            red[t].x += red[t + w].x; red[t].y += red[t + w].y;
            red[t].z += red[t + w].z; red[t].w += red[t + w].w;
        }
        __syncthreads();
    }
    if (t == 0) {
        out[0] = red[0].x / (float)NELEM + 0.1f * att_loss[0];
        out[1] = red[0].y / (float)NELEM;
        out[2] = red[0].z / (float)NELEM;
        out[3] = red[0].w / (float)NELEM;
    }
}

extern "C" void kernel_launch(void* const* d_in, const int* in_sizes, int n_in,
                              void* d_out, int out_size, void* d_ws, size_t ws_size,
                              hipStream_t stream) {
    const float* out_f        = (const float*)d_in[0];
    // d_in[1] = labels_support (unused by the reference's train path)
    const int*   labels_query = (const int*)d_in[2];
    const float* att_loss     = (const float*)d_in[3];
    float* out = (float*)d_out;

    // workspace layout
    float*  rowmean_q = (float*)d_ws;                           // 4800*8 f
    float*  proto_all = rowmean_q + QROWS * NUM_SLOT;           // 320*8*640 f
    float*  pn2_all   = proto_all + NGROUP * NUM_SLOT * DD;     // 2560 f
    float*  supm_g    = pn2_all + NGROUP * NUM_SLOT;            // 2560 f
    float4* part      = (float4*)(supm_g + NGROUP * NUM_SLOT);  // 1216 float4

    k_pass1<<<NGROUP + QROWS, 256, 0, stream>>>(out_f, rowmean_q, proto_all,
                                                pn2_all, supm_g);
    k_mid<<<NBLK, 256, 0, stream>>>(out_f, rowmean_q, proto_all, pn2_all,
                                    supm_g, labels_query, part);
    k_final<<<1, 256, 0, stream>>>(part, att_loss, out);
}

// Round 14
// 39.623 us; speedup vs baseline: 1.0747x; 1.0747x over previous
//
#include <hip/hip_runtime.h>

// Problem constants (match reference)
#define BB 64
#define N_WAY 5
#define N_SHOT 5
#define QUERY 15
#define NUM_SLOT 8
#define DD 640
#define IMGS (N_WAY * QUERY)      // 75
#define NS (BB * N_WAY * N_SHOT)  // 1600 support rows
#define QROWS (BB * IMGS)         // 4800 query rows
#define ROWSZ (NUM_SLOT * DD)     // 5120 floats per row
#define F4_PER_SLOT 160           // 640/4
#define NELEM (BB * IMGS)         // 4800 loss elements
#define NGROUP (BB * N_WAY)       // 320 support groups
#define PIECES 19                 // ceil(75/4) pieces per batch
#define NBLK (BB * PIECES)        // 1216 mid blocks (1 element per wave)

// ---------------- K1: single streaming pass over out_f ----------------
// Query rows -> rowmean_q[4800][8]. Support groups -> proto_all[320][8][640],
// pn2_all[320][8], supm_g[320][8] (= mean_d proto = mean over shot,d of raw).
__global__ __launch_bounds__(256) void k_pass1(const float* __restrict__ out_f,
                                               float* __restrict__ rowmean_q,
                                               float* __restrict__ proto_all,
                                               float* __restrict__ pn2_all,
                                               float* __restrict__ supm_g) {
    int b = blockIdx.x;
    int t = threadIdx.x;
    int slot = t >> 5;            // 0..7
    int l = t & 31;
    if (b < NGROUP) {
        const int g = b;          // support group j*5+c
        float4 acc[5];
        #pragma unroll
        for (int k = 0; k < 5; ++k) acc[k] = make_float4(0.f, 0.f, 0.f, 0.f);
        #pragma unroll
        for (int sh = 0; sh < N_SHOT; ++sh) {
            const float4* p = (const float4*)(out_f +
                ((size_t)((g * N_SHOT + sh) * NUM_SLOT + slot)) * DD);
            #pragma unroll
            for (int k = 0; k < 5; ++k) {
                float4 v = p[l + k * 32];
                acc[k].x += v.x; acc[k].y += v.y; acc[k].z += v.z; acc[k].w += v.w;
            }
        }
        float4* pp = (float4*)(proto_all + ((size_t)(g * NUM_SLOT + slot)) * DD);
        float ssq = 0.f, sm = 0.f;
        #pragma unroll
        for (int k = 0; k < 5; ++k) {
            acc[k].x *= 0.2f; acc[k].y *= 0.2f; acc[k].z *= 0.2f; acc[k].w *= 0.2f;
            pp[l + k * 32] = acc[k];
            ssq += acc[k].x * acc[k].x + acc[k].y * acc[k].y
                 + acc[k].z * acc[k].z + acc[k].w * acc[k].w;
            sm  += (acc[k].x + acc[k].y) + (acc[k].z + acc[k].w);
        }
        #pragma unroll
        for (int off = 16; off; off >>= 1) {
            ssq += __shfl_down(ssq, off, 32);
            sm  += __shfl_down(sm,  off, 32);
        }
        if (l == 0) {
            pn2_all[g * NUM_SLOT + slot] = ssq;
            supm_g[g * NUM_SLOT + slot]  = sm * (1.f / DD);
        }
    } else {
        int rq = b - NGROUP;         // query row index 0..4799
        const float4* p = (const float4*)(out_f + (size_t)(NS + rq) * ROWSZ)
                          + slot * F4_PER_SLOT;
        float s = 0.f;
        #pragma unroll
        for (int k = 0; k < 5; ++k) {
            float4 v = p[l + k * 32];
            s += (v.x + v.y) + (v.z + v.w);
        }
        #pragma unroll
        for (int off = 16; off; off >>= 1) s += __shfl_down(s, off, 32);
        if (l == 0) rowmean_q[rq * NUM_SLOT + slot] = s * (1.f / DD);
    }
}

// ---------------- K2: fused mid kernel, one element per wave (R10 shape) -------
// DENSE loads: lane i owns float2 chunks {i + 64k}, k=0..4, of each 640-dim
// vector (8B lane stride -> full cache-line utilization per instruction).
// q and proto use the same permutation so products pair; only the reduction's
// association order changes (error << threshold).
__global__ __launch_bounds__(256) void k_mid(const float* __restrict__ out_f,
                                             const float* __restrict__ rowmean_q,
                                             const float* __restrict__ proto_all,
                                             const float* __restrict__ pn2_all,
                                             const float* __restrict__ supm_g,
                                             const int* __restrict__ labels_query,
                                             float4* __restrict__ part) {
    int b = blockIdx.x;            // j*PIECES + piece
    int j = b / PIECES, piece = b - j * PIECES;
    int t = threadIdx.x;           // 256
    int wave = t >> 6, lane = t & 63;
    int m = piece * 4 + wave;      // element this wave owns (>=75 -> idle)

    __shared__ float qbt[NUM_SLOT][80];       // transposed query rowmeans
    __shared__ float supmS[N_WAY * NUM_SLOT];
    __shared__ int   msS[N_WAY];
    __shared__ float4 redS[4];

    // stage query row-means transposed (conflict-free argmax reads later)
    const float* qbase = rowmean_q + (size_t)j * IMGS * NUM_SLOT;
    if (t < 150) {
        float4 v = ((const float4*)qbase)[t];
        int s = t >> 1, sl0 = (t & 1) * 4;
        qbt[sl0 + 0][s] = v.x; qbt[sl0 + 1][s] = v.y;
        qbt[sl0 + 2][s] = v.z; qbt[sl0 + 3][s] = v.w;
    }
    // support slot-means (precomputed by pass1)
    if (t >= 192 && t < 192 + N_WAY * NUM_SLOT)
        supmS[t - 192] = supm_g[j * (N_WAY * NUM_SLOT) + (t - 192)];
    __syncthreads();

    // greedy cover select (serial, tiny; first-occurrence among untaken)
    if (t == 0) {
        unsigned taken = 0u;
        #pragma unroll
        for (int c = 0; c < N_WAY; ++c) {
            float best = -3.0e38f; int bi = 0;
            #pragma unroll
            for (int s = 0; s < NUM_SLOT; ++s) {
                float v = supmS[c * NUM_SLOT + s];
                if (!((taken >> s) & 1u) && v > best) { best = v; bi = s; }
            }
            taken |= (1u << bi);
            msS[c] = bi;
        }
    }
    __syncthreads();

    int ms[N_WAY];
    #pragma unroll
    for (int n = 0; n < N_WAY; ++n) ms[n] = msS[n];

    float4 lv = make_float4(0.f, 0.f, 0.f, 0.f);
    if (m < IMGS) {
        // q1 load early (row m, its class's selected slot) — DENSE
        const float2* q1p = (const float2*)(out_f +
            (size_t)(NS + j * IMGS + m) * ROWSZ + ms[m / QUERY] * DD);
        float2 q1v[5];
        #pragma unroll
        for (int k = 0; k < 5; ++k) q1v[k] = q1p[lane + 64 * k];

        // per-lane proto registers + pn2 — DENSE
        float2 pv[N_WAY][5];
        float p2r[N_WAY];
        #pragma unroll
        for (int n = 0; n < N_WAY; ++n) {
            const float2* pp = (const float2*)(proto_all +
                ((size_t)((j * N_WAY + n) * NUM_SLOT + ms[n])) * DD);
            #pragma unroll
            for (int k = 0; k < 5; ++k) pv[n][k] = pp[lane + 64 * k];
            p2r[n] = pn2_all[(j * N_WAY + n) * NUM_SLOT + ms[n]];
        }

        // per-wave argmax over flat candidates l = s*5+c, s in [0, m]
        // (first occurrence == max value, min flat index among ties)
        float bv = -3.0e38f; int bi = 0x7fffffff;
        #pragma unroll
        for (int rep = 0; rep < 2; ++rep) {
            int s = lane + rep * 64;
            if (s <= m) {
                #pragma unroll
                for (int c = 0; c < N_WAY; ++c) {
                    float x = qbt[ms[c]][s];          // consecutive -> conflict-free
                    int flat = s * N_WAY + c;
                    if (x > bv || (x == bv && flat < bi)) { bv = x; bi = flat; }
                }
            }
        }
        #pragma unroll
        for (int off = 32; off; off >>= 1) {
            float ov = __shfl_down(bv, off, 64);
            int   oi = __shfl_down(bi, off, 64);
            if (ov > bv || (ov == bv && oi < bi)) { bv = ov; bi = oi; }
        }
        bi = __shfl(bi, 0, 64);                       // broadcast winner
        int s2 = bi / N_WAY, c2 = bi - s2 * N_WAY;
        const float2* q2p = (const float2*)(out_f +
            (size_t)(NS + j * IMGS + s2) * ROWSZ + ms[c2] * DD);
        float2 q2v[5];
        #pragma unroll
        for (int k = 0; k < 5; ++k) q2v[k] = q2p[lane + 64 * k];

        float s1[N_WAY] = {0, 0, 0, 0, 0};
        float s2a[N_WAY] = {0, 0, 0, 0, 0};
        #pragma unroll
        for (int n = 0; n < N_WAY; ++n) {
            #pragma unroll
            for (int k = 0; k < 5; ++k) {
                s1[n]  += q1v[k].x * pv[n][k].x + q1v[k].y * pv[n][k].y;
                s2a[n] += q2v[k].x * pv[n][k].x + q2v[k].y * pv[n][k].y;
            }
        }
        #pragma unroll
        for (int n = 0; n < N_WAY; ++n) {
            #pragma unroll
            for (int off = 32; off; off >>= 1) {
                s1[n]  += __shfl_down(s1[n],  off, 64);
                s2a[n] += __shfl_down(s2a[n], off, 64);
            }
        }
        if (lane == 0) {
            int label = labels_query[j * IMGS + m];
            // path 1: li_n = 2 q.p_n - ||p_n||^2 (||q||^2 cancels)
            {
                float li[N_WAY]; float mx = -3.0e38f;
                #pragma unroll
                for (int n = 0; n < N_WAY; ++n) { li[n] = 2.f * s1[n] - p2r[n]; mx = fmaxf(mx, li[n]); }
                float se = 0.f;
                #pragma unroll
                for (int n = 0; n < N_WAY; ++n) se += expf(li[n] - mx);
                float lse = mx + logf(se);
                int bn = 0; float bvv = li[0];
                #pragma unroll
                for (int n = 1; n < N_WAY; ++n) if (li[n] > bvv) { bvv = li[n]; bn = n; }
                lv.x = -(li[label] - lse);
                lv.z = (bn == label) ? 1.f : 0.f;
            }
            // path 2
            {
                float li[N_WAY]; float mx = -3.0e38f;
                #pragma unroll
                for (int n = 0; n < N_WAY; ++n) { li[n] = 2.f * s2a[n] - p2r[n]; mx = fmaxf(mx, li[n]); }
                float se = 0.f;
                #pragma unroll
                for (int n = 0; n < N_WAY; ++n) se += expf(li[n] - mx);
                float lse = mx + logf(se);
                int bn = 0; float bvv = li[0];
                #pragma unroll
                for (int n = 1; n < N_WAY; ++n) if (li[n] > bvv) { bvv = li[n]; bn = n; }
                lv.y = -(li[label] - lse);
                lv.w = (bn == label) ? 1.f : 0.f;
            }
        }
    }
    if (lane == 0) redS[wave] = lv;        // idle waves write zeros
    __syncthreads();
    if (t == 0) {
        float4 s0 = redS[0], s1 = redS[1], s2 = redS[2], s3 = redS[3];
        part[b] = make_float4(s0.x + s1.x + s2.x + s3.x,
                              s0.y + s1.y + s2.y + s3.y,
                              s0.z + s1.z + s2.z + s3.z,
                              s0.w + s1.w + s2.w + s3.w);
    }
}

// ---------------- K3: final deterministic reduction (1216 float4) --------------
__global__ __launch_bounds__(256) void k_final(const float4* __restrict__ part,
                                               const float* __restrict__ att_loss,
                                               float* __restrict__ out) {
    __shared__ float4 red[256];
    int t = threadIdx.x;              // 256
    float4 s = make_float4(0.f, 0.f, 0.f, 0.f);
    for (int i = t; i < NBLK; i += 256) {
        float4 v = part[i];
        s.x += v.x; s.y += v.y; s.z += v.z; s.w += v.w;
    }
    red[t] = s;
    __syncthreads();
    for (int w = 128; w; w >>= 1) {
        if (t < w) {
            red[t].x += red[t + w].x; red[t].y += red[t + w].y;
            red[t].z += red[t + w].z; red[t].w += red[t + w].w;
        }
        __syncthreads();
    }
    if (t == 0) {
        out[0] = red[0].x / (float)NELEM + 0.1f * att_loss[0];
        out[1] = red[0].y / (float)NELEM;
        out[2] = red[0].z / (float)NELEM;
        out[3] = red[0].w / (float)NELEM;
    }
}

extern "C" void kernel_launch(void* const* d_in, const int* in_sizes, int n_in,
                              void* d_out, int out_size, void* d_ws, size_t ws_size,
                              hipStream_t stream) {
    const float* out_f        = (const float*)d_in[0];
    // d_in[1] = labels_support (unused by the reference's train path)
    const int*   labels_query = (const int*)d_in[2];
    const float* att_loss     = (const float*)d_in[3];
    float* out = (float*)d_out;

    // workspace layout
    float*  rowmean_q = (float*)d_ws;                           // 4800*8 f
    float*  proto_all = rowmean_q + QROWS * NUM_SLOT;           // 320*8*640 f
    float*  pn2_all   = proto_all + NGROUP * NUM_SLOT * DD;     // 2560 f
    float*  supm_g    = pn2_all + NGROUP * NUM_SLOT;            // 2560 f
    float4* part      = (float4*)(supm_g + NGROUP * NUM_SLOT);  // 1216 float4

    k_pass1<<<NGROUP + QROWS, 256, 0, stream>>>(out_f, rowmean_q, proto_all,
                                                pn2_all, supm_g);
    k_mid<<<NBLK, 256, 0, stream>>>(out_f, rowmean_q, proto_all, pn2_all,
                                    supm_g, labels_query, part);
    k_final<<<1, 256, 0, stream>>>(part, att_loss, out);
}